// Round 16
// baseline (2285.779 us; speedup 1.0000x reference)
//
#include <hip/hip_runtime.h>
#include <hip/hip_bf16.h>
#include <stdint.h>

// ConditionalLoRALinear: out = x@W^T + b + mask*(2*(x@A^T)@B^T)
// M=16384, K=4096, N=4096, R=8. bf16 MFMA path.
// R16: B-operand moved OUT of LDS into registers (direct global->VGPR frag
//      loads, prefetched 2 tiles ahead, counted vmcnt(10)). LDS is A-only
//      (80 KiB: 3-slot m0 ring + 2-buf m1) -> LDS pipe ~1925 cyc/tile drops
//      below MFMA 2483 -> matrix pipe becomes the binding pipe. Even/odd
//      B-register sets (static indexing); A path/schedule = verified R12.

typedef __attribute__((ext_vector_type(8))) __bf16 bf16x8;
typedef __attribute__((ext_vector_type(4))) float f32x4;

#define M_DIM 16384
#define K_DIM 4096
#define N_DIM 4096
#define BM 256
#define BN 256
#define BK 64
#define NT2 (K_DIM / BK)   // 64

// ---------------- merged W + lora_A f32 -> bf16 conversion ----------------
__global__ __launch_bounds__(256) void cvt_wa(
    const float* __restrict__ W, __hip_bfloat16* __restrict__ Wb,
    const float* __restrict__ A, __hip_bfloat16* __restrict__ Ab) {
    int b = blockIdx.x;
    if (b < 1024) {
        int i = b * 256 + threadIdx.x;
        const int n8 = N_DIM * K_DIM / 8;
        const int stride = 1024 * 256;
        for (; i < n8; i += stride) {
            const float4* p = (const float4*)(W + (size_t)i * 8);
            float4 v0 = p[0], v1 = p[1];
            bf16x8 o;
            o[0] = (__bf16)v0.x; o[1] = (__bf16)v0.y; o[2] = (__bf16)v0.z; o[3] = (__bf16)v0.w;
            o[4] = (__bf16)v1.x; o[5] = (__bf16)v1.y; o[6] = (__bf16)v1.z; o[7] = (__bf16)v1.w;
            *(bf16x8*)((__hip_bfloat16*)Wb + (size_t)i * 8) = o;
        }
    } else {
        int i = (b - 1024) * 256 + threadIdx.x;
        if (i < 8 * K_DIM / 8) {
            const float4* p = (const float4*)(A + (size_t)i * 8);
            float4 v0 = p[0], v1 = p[1];
            bf16x8 o;
            o[0] = (__bf16)v0.x; o[1] = (__bf16)v0.y; o[2] = (__bf16)v0.z; o[3] = (__bf16)v0.w;
            o[4] = (__bf16)v1.x; o[5] = (__bf16)v1.y; o[6] = (__bf16)v1.z; o[7] = (__bf16)v1.w;
            *(bf16x8*)((__hip_bfloat16*)Ab + (size_t)i * 8) = o;
        }
    }
}

// ---------------- fused: x -> Xb (bf16) AND xa[m][r] = 2*mask*dot(x[m],A[r]) ----------------
__global__ __launch_bounds__(256) void cvt_x_xa(
    const float* __restrict__ x, const int* __restrict__ ids,
    const __hip_bfloat16* __restrict__ Abf,   // [8,4096] bf16
    __hip_bfloat16* __restrict__ Xb, float* __restrict__ xa) {
    __shared__ __hip_bfloat16 As[8 * 4096];   // 64 KiB
    int tid = threadIdx.x;
    for (int i = tid; i < 8 * 4096 / 8; i += 256)
        *(bf16x8*)(As + i * 8) = *(const bf16x8*)(Abf + i * 8);
    __syncthreads();

    int wave = tid >> 6, lane = tid & 63;
#pragma unroll
    for (int rr = 0; rr < 2; rr++) {
        int row = blockIdx.x * 8 + wave * 2 + rr;
        const float* xr = x + (size_t)row * K_DIM;
        __hip_bfloat16* xo = Xb + (size_t)row * K_DIM;
        float s[8] = {0.f, 0.f, 0.f, 0.f, 0.f, 0.f, 0.f, 0.f};
#pragma unroll
        for (int j = 0; j < 8; j++) {
            int k = j * 512 + lane * 8;
            float4 v0 = *(const float4*)(xr + k);
            float4 v1 = *(const float4*)(xr + k + 4);
            bf16x8 o;
            o[0] = (__bf16)v0.x; o[1] = (__bf16)v0.y; o[2] = (__bf16)v0.z; o[3] = (__bf16)v0.w;
            o[4] = (__bf16)v1.x; o[5] = (__bf16)v1.y; o[6] = (__bf16)v1.z; o[7] = (__bf16)v1.w;
            *(bf16x8*)(xo + k) = o;
#pragma unroll
            for (int r = 0; r < 8; r++) {
                bf16x8 av = *(const bf16x8*)(As + r * 4096 + k);
                s[r] += v0.x * (float)av[0] + v0.y * (float)av[1] + v0.z * (float)av[2] + v0.w * (float)av[3]
                      + v1.x * (float)av[4] + v1.y * (float)av[5] + v1.z * (float)av[6] + v1.w * (float)av[7];
            }
        }
#pragma unroll
        for (int r = 0; r < 8; r++) {
            float v = s[r];
            for (int off = 32; off; off >>= 1) v += __shfl_down(v, off);
            s[r] = v;
        }
        if (lane == 0) {
            float gate = (ids[row] == 7) ? 2.0f : 0.0f;
#pragma unroll
            for (int r = 0; r < 8; r++) xa[(size_t)row * 8 + r] = s[r] * gate;
        }
    }
}

// ---------------- main GEMM ----------------
__device__ __forceinline__ void gload_lds16(const void* g, void* l) {
    __builtin_amdgcn_global_load_lds(
        (const __attribute__((address_space(1))) unsigned int*)g,
        (__attribute__((address_space(3))) unsigned int*)l, 16, 0, 0);
}

#define LGKMW(n) asm volatile("s_waitcnt lgkmcnt(" #n ")" ::: "memory")
#define VMCW(n)  asm volatile("s_waitcnt vmcnt(" #n ")" ::: "memory")
#define SB0()    __builtin_amdgcn_sched_barrier(0)
#define BAR()    __builtin_amdgcn_s_barrier()
#define PRIO(p)  __builtin_amdgcn_s_setprio(p)

// LDS (80 KiB, A only):
//   [0, 48K):   A-m0 ring, 3 slots of 16 KiB (slot = kt % 3)
//   [48K, 80K): A-m1, 2 buffers of 16 KiB (buf = kt & 1)
// Unit mq rows: [wr0: global mq*64..+63][wr1: 128+mq*64..+63]. Rows 128 B;
// 8 chunks of 16 B at position p = chunk ^ (row&7) (XOR swizzle; linear dest +
// inverse-swizzled global source).
// B: NO LDS — per-wave direct global->VGPR fragment loads, 8 per tile
// (bSet[ni*2+ks]), prefetched 2 tiles ahead, retired by the per-tile vmcnt(10).
__global__ __launch_bounds__(512, 1) void gemm_bias_lora(
    const __hip_bfloat16* __restrict__ Xb,   // [M, K]
    const __hip_bfloat16* __restrict__ Wb,   // [N, K]
    const float* __restrict__ bias,          // [N]
    const float* __restrict__ xa,            // [M, 8] pre-scaled & gated
    const float* __restrict__ loraB,         // [N, 8]
    float* __restrict__ out) {
    __shared__ char smem[81920];             // 80 KiB

    int tid = threadIdx.x;
    int bid = blockIdx.x;
    int swz = (bid & 7) * 128 + (bid >> 3);  // XCD-bijective, nwg=1024
    int n_tile = swz & 15;
    int m_tile = swz >> 4;
    int m_base = m_tile * BM, n_base = n_tile * BN;
    int wave = tid >> 6, lane = tid & 63;
    int wr = wave >> 2, wc = wave & 3;       // 2M x 4N waves, per-wave 128x64
    int l15 = lane & 15, lhi = lane >> 4;
    int l8 = lane >> 3;
    int cx = ((lane & 7) ^ l8) * 16;          // staging source chunk (inverse swizzle)
    int pswz0 = ((lhi)     ^ (l15 & 7)) * 16; // read chunk byte, ks=0
    int pswz1 = ((4 + lhi) ^ (l15 & 7)) * 16; // read chunk byte, ks=1

    f32x4 acc[8][4] = {};

    const char* Abase = (const char*)(Xb + (size_t)m_base * K_DIM);
    // per-lane B fragment base: row (n_base + wc*64 + l15), k-byte lhi*16
    const char* Bfrag = (const char*)(Wb + (size_t)(n_base + wc * 64 + l15) * K_DIM) + lhi * 16;

    auto stage_Au = [&](int kt, int mq, char* ubase) {
#pragma unroll
        for (int j = 0; j < 2; j++) {
            int rg = wave * 2 + j;
            int rl = rg * 8 + l8;
            int g = (rl < 64) ? (mq * 64 + rl) : (128 + mq * 64 + (rl - 64));
            gload_lds16(Abase + (size_t)g * (K_DIM * 2) + (size_t)kt * 128 + cx,
                        ubase + rg * 1024 + lane * 16);
        }
    };

#define LOAD_B(kt, dst) do {                                                   \
        const char* bb = Bfrag + (size_t)(kt) * 128;                           \
        _Pragma("unroll")                                                      \
        for (int ni = 0; ni < 4; ni++) {                                       \
            dst[ni * 2 + 0] = *(const bf16x8*)(bb + (size_t)ni * (16 * K_DIM * 2));      \
            dst[ni * 2 + 1] = *(const bf16x8*)(bb + (size_t)ni * (16 * K_DIM * 2) + 64); \
        }                                                                      \
    } while (0)

    bf16x8 bE[8], bO[8];
    bf16x8 af0[4], af1[4];

    // prologue: B(0)->bE(8), A tile0 (4), A-m0(1) (2), B(1)->bO(8) = 22 issued
    LOAD_B(0, bE);
    stage_Au(0, 0, smem);
    stage_Au(0, 1, smem + 49152);
    stage_Au(1, 0, smem + 16384);
    LOAD_B(1, bO);
    VMCW(10);        // retire bE(8) + A-tile0(4); leaves A-m0(1)(2) + bO(8)
    BAR();

    int s0 = 0;

    // Per-tile: issue order = [Am1(t+1) 2 @P1][Am0(t+2) 2 @P3][B(t+2) 8 @end].
    // End-of-tile VMCW(10) retires exactly {Am0(t+1), B(t+1), Am1(t+1)}.
    // B(t+2) loads into the CURRENT set (dead after this tile's last MFMA).
#define TILE(t, bC) {                                                          \
        int s2 = s0 + 2; if (s2 >= 3) s2 -= 3;                                 \
        const char* aU0 = smem + s0 * 16384 + (wr * 64 + l15) * 128;           \
        const char* aU1 = smem + 49152 + ((t) & 1) * 16384 + (wr * 64 + l15) * 128; \
        /* P0: reads af0(ks0)+ahead af1(ks0); MFMA af0 x bC[ks0] */            \
        _Pragma("unroll")                                                      \
        for (int mi = 0; mi < 4; mi++) af0[mi] = *(const bf16x8*)(aU0 + mi * 2048 + pswz0); \
        _Pragma("unroll")                                                      \
        for (int mi = 0; mi < 4; mi++) af1[mi] = *(const bf16x8*)(aU1 + mi * 2048 + pswz0); \
        LGKMW(4); SB0();                                                       \
        PRIO(1);                                                               \
        _Pragma("unroll")                                                      \
        for (int mi = 0; mi < 4; mi++) {                                       \
            acc[mi][0] = __builtin_amdgcn_mfma_f32_16x16x32_bf16(af0[mi], bC[0], acc[mi][0], 0, 0, 0); \
            acc[mi][1] = __builtin_amdgcn_mfma_f32_16x16x32_bf16(af0[mi], bC[2], acc[mi][1], 0, 0, 0); \
            acc[mi][2] = __builtin_amdgcn_mfma_f32_16x16x32_bf16(af0[mi], bC[4], acc[mi][2], 0, 0, 0); \
            acc[mi][3] = __builtin_amdgcn_mfma_f32_16x16x32_bf16(af0[mi], bC[6], acc[mi][3], 0, 0, 0); \
        }                                                                      \
        PRIO(0);                                                               \
        /* P1: ahead read af0(ks1); stage A-m1(t+1); MFMA af1 x bC[ks0] */     \
        _Pragma("unroll")                                                      \
        for (int mi = 0; mi < 4; mi++) af0[mi] = *(const bf16x8*)(aU0 + mi * 2048 + pswz1); \
        if ((t) + 1 < NT2) stage_Au((t) + 1, 1, smem + 49152 + (((t) + 1) & 1) * 16384); \
        LGKMW(4); SB0();                                                       \
        PRIO(1);                                                               \
        _Pragma("unroll")                                                      \
        for (int mi = 0; mi < 4; mi++) {                                       \
            acc[4 + mi][0] = __builtin_amdgcn_mfma_f32_16x16x32_bf16(af1[mi], bC[0], acc[4 + mi][0], 0, 0, 0); \
            acc[4 + mi][1] = __builtin_amdgcn_mfma_f32_16x16x32_bf16(af1[mi], bC[2], acc[4 + mi][1], 0, 0, 0); \
            acc[4 + mi][2] = __builtin_amdgcn_mfma_f32_16x16x32_bf16(af1[mi], bC[4], acc[4 + mi][2], 0, 0, 0); \
            acc[4 + mi][3] = __builtin_amdgcn_mfma_f32_16x16x32_bf16(af1[mi], bC[6], acc[4 + mi][3], 0, 0, 0); \
        }                                                                      \
        PRIO(0);                                                               \
        /* P2: ahead read af1(ks1); MFMA af0 x bC[ks1] */                      \
        _Pragma("unroll")                                                      \
        for (int mi = 0; mi < 4; mi++) af1[mi] = *(const bf16x8*)(aU1 + mi * 2048 + pswz1); \
        LGKMW(4); SB0();                                                       \
        PRIO(1);                                                               \
        _Pragma("unroll")                                                      \
        for (int mi = 0; mi < 4; mi++) {                                       \
            acc[mi][0] = __builtin_amdgcn_mfma_f32_16x16x32_bf16(af0[mi], bC[1], acc[mi][0], 0, 0, 0); \
            acc[mi][1] = __builtin_amdgcn_mfma_f32_16x16x32_bf16(af0[mi], bC[3], acc[mi][1], 0, 0, 0); \
            acc[mi][2] = __builtin_amdgcn_mfma_f32_16x16x32_bf16(af0[mi], bC[5], acc[mi][2], 0, 0, 0); \
            acc[mi][3] = __builtin_amdgcn_mfma_f32_16x16x32_bf16(af0[mi], bC[7], acc[mi][3], 0, 0, 0); \
        }                                                                      \
        PRIO(0);                                                               \
        /* P3: stage A-m0(t+2); MFMA af1 x bC[ks1]; then B(t+2) -> bC */       \
        if ((t) + 2 < NT2) stage_Au((t) + 2, 0, smem + s2 * 16384);            \
        LGKMW(0); SB0();                                                       \
        PRIO(1);                                                               \
        _Pragma("unroll")                                                      \
        for (int mi = 0; mi < 4; mi++) {                                       \
            acc[4 + mi][0] = __builtin_amdgcn_mfma_f32_16x16x32_bf16(af1[mi], bC[1], acc[4 + mi][0], 0, 0, 0); \
            acc[4 + mi][1] = __builtin_amdgcn_mfma_f32_16x16x32_bf16(af1[mi], bC[3], acc[4 + mi][1], 0, 0, 0); \
            acc[4 + mi][2] = __builtin_amdgcn_mfma_f32_16x16x32_bf16(af1[mi], bC[5], acc[4 + mi][2], 0, 0, 0); \
            acc[4 + mi][3] = __builtin_amdgcn_mfma_f32_16x16x32_bf16(af1[mi], bC[7], acc[4 + mi][3], 0, 0, 0); \
        }                                                                      \
        PRIO(0);                                                               \
        if ((t) + 2 < NT2) LOAD_B((t) + 2, bC);                                \
        if ((t) < NT2 - 2) { VMCW(10); } else { VMCW(0); }                     \
        BAR();                                                                 \
        s0 = s0 + 1; if (s0 >= 3) s0 -= 3;                                     \
    }

    for (int tt = 0; tt < NT2; tt += 2) {
        TILE(tt, bE);
        TILE(tt + 1, bO);
    }
#undef TILE
#undef LOAD_B

    // epilogue: C/D layout col = lane&15, row = (lane>>4)*4 + reg
    int wrow = m_base + wr * 128;
    int wcol = n_base + wc * 64;
    float bv[4];
    float4 lb0[4], lb1[4];
#pragma unroll
    for (int ni = 0; ni < 4; ni++) {
        int n = wcol + ni * 16 + l15;
        bv[ni] = bias[n];
        lb0[ni] = *(const float4*)(loraB + (size_t)n * 8);
        lb1[ni] = *(const float4*)(loraB + (size_t)n * 8 + 4);
    }
#pragma unroll
    for (int mi = 0; mi < 8; mi++) {
#pragma unroll
        for (int r = 0; r < 4; r++) {
            int m = wrow + mi * 16 + lhi * 4 + r;
            float4 xa0 = *(const float4*)(xa + (size_t)m * 8);
            float4 xa1 = *(const float4*)(xa + (size_t)m * 8 + 4);
#pragma unroll
            for (int ni = 0; ni < 4; ni++) {
                int n = wcol + ni * 16 + l15;
                float lora = xa0.x * lb0[ni].x + xa0.y * lb0[ni].y + xa0.z * lb0[ni].z + xa0.w * lb0[ni].w
                           + xa1.x * lb1[ni].x + xa1.y * lb1[ni].y + xa1.z * lb1[ni].z + xa1.w * lb1[ni].w;
                out[(size_t)m * N_DIM + n] = acc[mi][ni][r] + bv[ni] + lora;
            }
        }
    }
}

// ---------------- fallback (ws too small): correct but slow ----------------
__global__ void fallback_kernel(const float* __restrict__ x, const int* __restrict__ ids,
                                const float* __restrict__ W, const float* __restrict__ b,
                                const float* __restrict__ A, const float* __restrict__ B8,
                                float* __restrict__ out) {
    __shared__ float xs[K_DIM];
    __shared__ float xa_s[8];
    int row = blockIdx.y;
    int t = threadIdx.x;
    const float* xr = x + (size_t)row * K_DIM;
    for (int k = t; k < K_DIM; k += 256) xs[k] = xr[k];
    __syncthreads();
    if (t < 8) {
        float s = 0.f;
        for (int k = 0; k < K_DIM; k++) s += xs[k] * A[t * K_DIM + k];
        xa_s[t] = (ids[row] == 7) ? s * 2.0f : 0.0f;
    }
    __syncthreads();
    int col = blockIdx.x * 256 + t;
    const float* wr = W + (size_t)col * K_DIM;
    float acc = 0.f;
    for (int k = 0; k < K_DIM; k++) acc += xs[k] * wr[k];
    float lora = 0.f;
#pragma unroll
    for (int rr = 0; rr < 8; rr++) lora += xa_s[rr] * B8[col * 8 + rr];
    out[(size_t)row * N_DIM + col] = acc + b[col] + lora;
}

extern "C" void kernel_launch(void* const* d_in, const int* in_sizes, int n_in,
                              void* d_out, int out_size, void* d_ws, size_t ws_size,
                              hipStream_t stream) {
    const float* x   = (const float*)d_in[0];
    const int*   ids = (const int*)d_in[1];
    const float* W   = (const float*)d_in[2];
    const float* b   = (const float*)d_in[3];
    const float* lA  = (const float*)d_in[4];
    const float* lB  = (const float*)d_in[5];
    float* out = (float*)d_out;

    size_t wb_bytes = (size_t)N_DIM * K_DIM * 2;          // 32 MiB
    size_t xb_bytes = (size_t)M_DIM * K_DIM * 2;          // 128 MiB
    size_t xa_bytes = (size_t)M_DIM * 8 * 4;              // 0.5 MiB
    size_t ab_bytes = (size_t)8 * K_DIM * 2;              // 64 KiB

    if (ws_size >= wb_bytes + xb_bytes + xa_bytes + ab_bytes) {
        __hip_bfloat16* Wb  = (__hip_bfloat16*)d_ws;
        __hip_bfloat16* Xb  = (__hip_bfloat16*)((char*)d_ws + wb_bytes);
        float*          xav = (float*)((char*)d_ws + wb_bytes + xb_bytes);
        __hip_bfloat16* Abf = (__hip_bfloat16*)((char*)d_ws + wb_bytes + xb_bytes + xa_bytes);

        cvt_wa<<<1024 + 16, 256, 0, stream>>>(W, Wb, lA, Abf);
        cvt_x_xa<<<M_DIM / 8, 256, 0, stream>>>(x, ids, Abf, Xb, xav);
        gemm_bias_lora<<<(M_DIM / BM) * (N_DIM / BN), 512, 0, stream>>>(Xb, Wb, b, xav, lB, out);
    } else {
        fallback_kernel<<<dim3(N_DIM / 256, M_DIM), 256, 0, stream>>>(x, ids, W, b, lA, lB, out);
    }
}

// Round 17
// 570.937 us; speedup vs baseline: 4.0036x; 4.0036x over previous
//
#include <hip/hip_runtime.h>
#include <hip/hip_bf16.h>
#include <stdint.h>

// ConditionalLoRALinear: out = x@W^T + b + mask*(2*(x@A^T)@B^T)
// M=16384, K=4096, N=4096, R=8. bf16 MFMA path.
// R17: revert to verified R15/R12 config (572us total; GEMM 475us @ MfmaUtil
//      56.6, 0 conflicts; prep at HBM ceiling). R16's B-in-registers refuted:
//      unified VGPR/AGPR file -> 128 acc AGPRs + 64 B-regs exceed the 256/wave
//      budget at 2 waves/SIMD -> scratch spills (WRITE_SIZE 262MB -> 2.97GB).

typedef __attribute__((ext_vector_type(8))) __bf16 bf16x8;
typedef __attribute__((ext_vector_type(4))) float f32x4;

#define M_DIM 16384
#define K_DIM 4096
#define N_DIM 4096
#define BM 256
#define BN 256
#define BK 64
#define NT2 (K_DIM / BK)   // 64

// ---------------- merged W + lora_A f32 -> bf16 conversion ----------------
__global__ __launch_bounds__(256) void cvt_wa(
    const float* __restrict__ W, __hip_bfloat16* __restrict__ Wb,
    const float* __restrict__ A, __hip_bfloat16* __restrict__ Ab) {
    int b = blockIdx.x;
    if (b < 1024) {
        int i = b * 256 + threadIdx.x;
        const int n8 = N_DIM * K_DIM / 8;
        const int stride = 1024 * 256;
        for (; i < n8; i += stride) {
            const float4* p = (const float4*)(W + (size_t)i * 8);
            float4 v0 = p[0], v1 = p[1];
            bf16x8 o;
            o[0] = (__bf16)v0.x; o[1] = (__bf16)v0.y; o[2] = (__bf16)v0.z; o[3] = (__bf16)v0.w;
            o[4] = (__bf16)v1.x; o[5] = (__bf16)v1.y; o[6] = (__bf16)v1.z; o[7] = (__bf16)v1.w;
            *(bf16x8*)((__hip_bfloat16*)Wb + (size_t)i * 8) = o;
        }
    } else {
        int i = (b - 1024) * 256 + threadIdx.x;
        if (i < 8 * K_DIM / 8) {
            const float4* p = (const float4*)(A + (size_t)i * 8);
            float4 v0 = p[0], v1 = p[1];
            bf16x8 o;
            o[0] = (__bf16)v0.x; o[1] = (__bf16)v0.y; o[2] = (__bf16)v0.z; o[3] = (__bf16)v0.w;
            o[4] = (__bf16)v1.x; o[5] = (__bf16)v1.y; o[6] = (__bf16)v1.z; o[7] = (__bf16)v1.w;
            *(bf16x8*)((__hip_bfloat16*)Ab + (size_t)i * 8) = o;
        }
    }
}

// ---------------- fused: x -> Xb (bf16) AND xa[m][r] = 2*mask*dot(x[m],A[r]) ----------------
__global__ __launch_bounds__(256) void cvt_x_xa(
    const float* __restrict__ x, const int* __restrict__ ids,
    const __hip_bfloat16* __restrict__ Abf,   // [8,4096] bf16
    __hip_bfloat16* __restrict__ Xb, float* __restrict__ xa) {
    __shared__ __hip_bfloat16 As[8 * 4096];   // 64 KiB
    int tid = threadIdx.x;
    for (int i = tid; i < 8 * 4096 / 8; i += 256)
        *(bf16x8*)(As + i * 8) = *(const bf16x8*)(Abf + i * 8);
    __syncthreads();

    int wave = tid >> 6, lane = tid & 63;
#pragma unroll
    for (int rr = 0; rr < 2; rr++) {
        int row = blockIdx.x * 8 + wave * 2 + rr;
        const float* xr = x + (size_t)row * K_DIM;
        __hip_bfloat16* xo = Xb + (size_t)row * K_DIM;
        float s[8] = {0.f, 0.f, 0.f, 0.f, 0.f, 0.f, 0.f, 0.f};
#pragma unroll
        for (int j = 0; j < 8; j++) {
            int k = j * 512 + lane * 8;
            float4 v0 = *(const float4*)(xr + k);
            float4 v1 = *(const float4*)(xr + k + 4);
            bf16x8 o;
            o[0] = (__bf16)v0.x; o[1] = (__bf16)v0.y; o[2] = (__bf16)v0.z; o[3] = (__bf16)v0.w;
            o[4] = (__bf16)v1.x; o[5] = (__bf16)v1.y; o[6] = (__bf16)v1.z; o[7] = (__bf16)v1.w;
            *(bf16x8*)(xo + k) = o;
#pragma unroll
            for (int r = 0; r < 8; r++) {
                bf16x8 av = *(const bf16x8*)(As + r * 4096 + k);
                s[r] += v0.x * (float)av[0] + v0.y * (float)av[1] + v0.z * (float)av[2] + v0.w * (float)av[3]
                      + v1.x * (float)av[4] + v1.y * (float)av[5] + v1.z * (float)av[6] + v1.w * (float)av[7];
            }
        }
#pragma unroll
        for (int r = 0; r < 8; r++) {
            float v = s[r];
            for (int off = 32; off; off >>= 1) v += __shfl_down(v, off);
            s[r] = v;
        }
        if (lane == 0) {
            float gate = (ids[row] == 7) ? 2.0f : 0.0f;
#pragma unroll
            for (int r = 0; r < 8; r++) xa[(size_t)row * 8 + r] = s[r] * gate;
        }
    }
}

// ---------------- main GEMM (VERIFIED R10/R12/R15 kernel) ----------------
__device__ __forceinline__ void gload_lds16(const void* g, void* l) {
    __builtin_amdgcn_global_load_lds(
        (const __attribute__((address_space(1))) unsigned int*)g,
        (__attribute__((address_space(3))) unsigned int*)l, 16, 0, 0);
}

#define LGKMW(n) asm volatile("s_waitcnt lgkmcnt(" #n ")" ::: "memory")
#define VMCW(n)  asm volatile("s_waitcnt vmcnt(" #n ")" ::: "memory")
#define SB0()    __builtin_amdgcn_sched_barrier(0)
#define BAR()    __builtin_amdgcn_s_barrier()
#define PRIO(p)  __builtin_amdgcn_s_setprio(p)

// LDS layout (144 KiB):
//   [0, 48K):    A-m0 ring, 3 slots of 16 KiB (slot = kt % 3)
//   [48K, 80K):  A-m1, 2 buffers of 16 KiB (buf = kt & 1)
//   [80K, 144K): B, 2 buffers of 32 KiB (buf = kt & 1)
// Unit mq rows: [wr0: global mq*64..+63][wr1: 128+mq*64..+63]. Rows 128 B;
// 8 chunks of 16 B at position p = chunk ^ (row&7) (XOR swizzle; linear dest +
// inverse-swizzled global source). All of tile t resident at tile-entry barrier.
__global__ __launch_bounds__(512, 1) void gemm_bias_lora(
    const __hip_bfloat16* __restrict__ Xb,   // [M, K]
    const __hip_bfloat16* __restrict__ Wb,   // [N, K]
    const float* __restrict__ bias,          // [N]
    const float* __restrict__ xa,            // [M, 8] pre-scaled & gated
    const float* __restrict__ loraB,         // [N, 8]
    float* __restrict__ out) {
    __shared__ char smem[147456];            // 144 KiB

    int tid = threadIdx.x;
    int bid = blockIdx.x;
    int swz = (bid & 7) * 128 + (bid >> 3);  // XCD-bijective, nwg=1024
    int n_tile = swz & 15;
    int m_tile = swz >> 4;
    int m_base = m_tile * BM, n_base = n_tile * BN;
    int wave = tid >> 6, lane = tid & 63;
    int wr = wave >> 2, wc = wave & 3;       // 2M x 4N waves, per-wave 128x64
    int l15 = lane & 15, lhi = lane >> 4;
    int l8 = lane >> 3;
    int cx = ((lane & 7) ^ l8) * 16;          // staging source chunk (inverse swizzle)
    int pswz0 = ((lhi)     ^ (l15 & 7)) * 16; // read chunk byte, ks=0
    int pswz1 = ((4 + lhi) ^ (l15 & 7)) * 16; // read chunk byte, ks=1
    int psA = wr ? pswz1 : pswz0;             // SIMD-pair skew (verified neutral)
    int psB = wr ? pswz0 : pswz1;

    f32x4 acc[8][4] = {};

    const char* Abase = (const char*)(Xb + (size_t)m_base * K_DIM);
    const char* Bbase = (const char*)(Wb + (size_t)n_base * K_DIM);

    auto stage_Au = [&](int kt, int mq, char* ubase) {
#pragma unroll
        for (int j = 0; j < 2; j++) {
            int rg = wave * 2 + j;
            int rl = rg * 8 + l8;
            int g = (rl < 64) ? (mq * 64 + rl) : (128 + mq * 64 + (rl - 64));
            gload_lds16(Abase + (size_t)g * (K_DIM * 2) + (size_t)kt * 128 + cx,
                        ubase + rg * 1024 + lane * 16);
        }
    };
    auto stage_B = [&](int kt, int h, int buf) {
        char* ub = smem + 81920 + buf * 32768 + h * 16384;
#pragma unroll
        for (int j = 0; j < 2; j++) {
            int rg = wave * 2 + j;
            int row = h * 128 + rg * 8 + l8;
            gload_lds16(Bbase + (size_t)row * (K_DIM * 2) + (size_t)kt * 128 + cx,
                        ub + rg * 1024 + lane * 16);
        }
    };

    // prologue: tile0 {A-m0 slot0, B buf0 h0/h1, A-m1 buf0} + A-m0(1) slot1
    stage_Au(0, 0, smem);
    stage_B(0, 0, 0); stage_B(0, 1, 0);
    stage_Au(0, 1, smem + 49152);
    stage_Au(1, 0, smem + 16384);
    VMCW(2);
    BAR();

    bf16x8 af0[4], af1[4], bf0[4], bf1[4];
    int s0 = 0;

    for (int t = 0; t < NT2; t++) {
        int cb = t & 1, nb = cb ^ 1;
        int s2 = s0 + 2; if (s2 >= 3) s2 -= 3;
        const char* aU0 = smem + s0 * 16384 + (wr * 64 + l15) * 128;
        const char* aU1 = smem + 49152 + cb * 16384 + (wr * 64 + l15) * 128;
        const char* bRb = smem + 81920 + cb * 32768 + (wc * 64 + l15) * 128;

        // ---- P0: reads af0(ksA), bf0(ksA) + ahead af1(ksA); stage B-h0(t+1) ----
#pragma unroll
        for (int mi = 0; mi < 4; mi++) af0[mi] = *(const bf16x8*)(aU0 + mi * 2048 + psA);
#pragma unroll
        for (int ni = 0; ni < 4; ni++) bf0[ni] = *(const bf16x8*)(bRb + ni * 2048 + psA);
#pragma unroll
        for (int mi = 0; mi < 4; mi++) af1[mi] = *(const bf16x8*)(aU1 + mi * 2048 + psA);
        if (t + 1 < NT2) stage_B(t + 1, 0, nb);
        LGKMW(4); SB0();
        PRIO(1);
#pragma unroll
        for (int mi = 0; mi < 4; mi++)
#pragma unroll
            for (int ni = 0; ni < 4; ni++)
                acc[mi][ni] = __builtin_amdgcn_mfma_f32_16x16x32_bf16(af0[mi], bf0[ni], acc[mi][ni], 0, 0, 0);
        PRIO(0);

        // ---- P1: ahead reads af0(ksB), bf1(ksB); stage B-h1(t+1), A-m1(t+1); MFMA af1xbf0 ----
#pragma unroll
        for (int mi = 0; mi < 4; mi++) af0[mi] = *(const bf16x8*)(aU0 + mi * 2048 + psB);
#pragma unroll
        for (int ni = 0; ni < 4; ni++) bf1[ni] = *(const bf16x8*)(bRb + ni * 2048 + psB);
        if (t + 1 < NT2) { stage_B(t + 1, 1, nb); stage_Au(t + 1, 1, smem + 49152 + nb * 16384); }
        LGKMW(8); SB0();
        PRIO(1);
#pragma unroll
        for (int mi = 0; mi < 4; mi++)
#pragma unroll
            for (int ni = 0; ni < 4; ni++)
                acc[4 + mi][ni] = __builtin_amdgcn_mfma_f32_16x16x32_bf16(af1[mi], bf0[ni], acc[4 + mi][ni], 0, 0, 0);
        PRIO(0);

        // ---- P2: ahead read af1(ksB); MFMA af0xbf1 ----
#pragma unroll
        for (int mi = 0; mi < 4; mi++) af1[mi] = *(const bf16x8*)(aU1 + mi * 2048 + psB);
        LGKMW(4); SB0();
        PRIO(1);
#pragma unroll
        for (int mi = 0; mi < 4; mi++)
#pragma unroll
            for (int ni = 0; ni < 4; ni++)
                acc[mi][ni] = __builtin_amdgcn_mfma_f32_16x16x32_bf16(af0[mi], bf1[ni], acc[mi][ni], 0, 0, 0);
        PRIO(0);

        // ---- P3: stage A-m0(t+2) -> ring slot s2; MFMA af1xbf1 ----
        if (t + 2 < NT2) stage_Au(t + 2, 0, smem + s2 * 16384);
        LGKMW(0); SB0();
        PRIO(1);
#pragma unroll
        for (int mi = 0; mi < 4; mi++)
#pragma unroll
            for (int ni = 0; ni < 4; ni++)
                acc[4 + mi][ni] = __builtin_amdgcn_mfma_f32_16x16x32_bf16(af1[mi], bf1[ni], acc[4 + mi][ni], 0, 0, 0);
        PRIO(0);
        if (t < NT2 - 2) { VMCW(2); } else { VMCW(0); }
        BAR();

        s0 = s0 + 1; if (s0 >= 3) s0 -= 3;
    }

    // epilogue: C/D layout col = lane&15, row = (lane>>4)*4 + reg
    int wrow = m_base + wr * 128;
    int wcol = n_base + wc * 64;
    float bv[4];
    float4 lb0[4], lb1[4];
#pragma unroll
    for (int ni = 0; ni < 4; ni++) {
        int n = wcol + ni * 16 + l15;
        bv[ni] = bias[n];
        lb0[ni] = *(const float4*)(loraB + (size_t)n * 8);
        lb1[ni] = *(const float4*)(loraB + (size_t)n * 8 + 4);
    }
#pragma unroll
    for (int mi = 0; mi < 8; mi++) {
#pragma unroll
        for (int r = 0; r < 4; r++) {
            int m = wrow + mi * 16 + lhi * 4 + r;
            float4 xa0 = *(const float4*)(xa + (size_t)m * 8);
            float4 xa1 = *(const float4*)(xa + (size_t)m * 8 + 4);
#pragma unroll
            for (int ni = 0; ni < 4; ni++) {
                int n = wcol + ni * 16 + l15;
                float lora = xa0.x * lb0[ni].x + xa0.y * lb0[ni].y + xa0.z * lb0[ni].z + xa0.w * lb0[ni].w
                           + xa1.x * lb1[ni].x + xa1.y * lb1[ni].y + xa1.z * lb1[ni].z + xa1.w * lb1[ni].w;
                out[(size_t)m * N_DIM + n] = acc[mi][ni][r] + bv[ni] + lora;
            }
        }
    }
}

// ---------------- fallback (ws too small): correct but slow ----------------
__global__ void fallback_kernel(const float* __restrict__ x, const int* __restrict__ ids,
                                const float* __restrict__ W, const float* __restrict__ b,
                                const float* __restrict__ A, const float* __restrict__ B8,
                                float* __restrict__ out) {
    __shared__ float xs[K_DIM];
    __shared__ float xa_s[8];
    int row = blockIdx.y;
    int t = threadIdx.x;
    const float* xr = x + (size_t)row * K_DIM;
    for (int k = t; k < K_DIM; k += 256) xs[k] = xr[k];
    __syncthreads();
    if (t < 8) {
        float s = 0.f;
        for (int k = 0; k < K_DIM; k++) s += xs[k] * A[t * K_DIM + k];
        xa_s[t] = (ids[row] == 7) ? s * 2.0f : 0.0f;
    }
    __syncthreads();
    int col = blockIdx.x * 256 + t;
    const float* wr = W + (size_t)col * K_DIM;
    float acc = 0.f;
    for (int k = 0; k < K_DIM; k++) acc += xs[k] * wr[k];
    float lora = 0.f;
#pragma unroll
    for (int rr = 0; rr < 8; rr++) lora += xa_s[rr] * B8[col * 8 + rr];
    out[(size_t)row * N_DIM + col] = acc + b[col] + lora;
}

extern "C" void kernel_launch(void* const* d_in, const int* in_sizes, int n_in,
                              void* d_out, int out_size, void* d_ws, size_t ws_size,
                              hipStream_t stream) {
    const float* x   = (const float*)d_in[0];
    const int*   ids = (const int*)d_in[1];
    const float* W   = (const float*)d_in[2];
    const float* b   = (const float*)d_in[3];
    const float* lA  = (const float*)d_in[4];
    const float* lB  = (const float*)d_in[5];
    float* out = (float*)d_out;

    size_t wb_bytes = (size_t)N_DIM * K_DIM * 2;          // 32 MiB
    size_t xb_bytes = (size_t)M_DIM * K_DIM * 2;          // 128 MiB
    size_t xa_bytes = (size_t)M_DIM * 8 * 4;              // 0.5 MiB
    size_t ab_bytes = (size_t)8 * K_DIM * 2;              // 64 KiB

    if (ws_size >= wb_bytes + xb_bytes + xa_bytes + ab_bytes) {
        __hip_bfloat16* Wb  = (__hip_bfloat16*)d_ws;
        __hip_bfloat16* Xb  = (__hip_bfloat16*)((char*)d_ws + wb_bytes);
        float*          xav = (float*)((char*)d_ws + wb_bytes + xb_bytes);
        __hip_bfloat16* Abf = (__hip_bfloat16*)((char*)d_ws + wb_bytes + xb_bytes + xa_bytes);

        cvt_wa<<<1024 + 16, 256, 0, stream>>>(W, Wb, lA, Abf);
        cvt_x_xa<<<M_DIM / 8, 256, 0, stream>>>(x, ids, Abf, Xb, xav);
        gemm_bias_lora<<<(M_DIM / BM) * (N_DIM / BN), 512, 0, stream>>>(Xb, Wb, b, xav, lB, out);
    } else {
        fallback_kernel<<<dim3(N_DIM / 256, M_DIM), 256, 0, stream>>>(x, ids, W, b, lA, lB, out);
    }
}

// Round 18
// 565.089 us; speedup vs baseline: 4.0450x; 1.0103x over previous
//
#include <hip/hip_runtime.h>
#include <hip/hip_bf16.h>
#include <stdint.h>

// ConditionalLoRALinear: out = x@W^T + b + mask*(2*(x@A^T)@B^T)
// M=16384, K=4096, N=4096, R=8. bf16 MFMA path.
// R18: R12 dataflow, unrolled x6 (ring3 x dbuf2 period) with compile-time
//      (s0,cb) per body -> all ds_reads are base+literal-offset, all gloads
//      are pointer+k*128 with 8 base pointers bumped once per 6 tiles.
//      Pure addressing strength-reduction; memory ops / wait ledger / swizzle
//      identical to the verified R12 (475us GEMM).

typedef __attribute__((ext_vector_type(8))) __bf16 bf16x8;
typedef __attribute__((ext_vector_type(4))) float f32x4;

#define M_DIM 16384
#define K_DIM 4096
#define N_DIM 4096
#define BM 256
#define BN 256
#define BK 64
#define NT2 (K_DIM / BK)   // 64

// ---------------- merged W + lora_A f32 -> bf16 conversion ----------------
__global__ __launch_bounds__(256) void cvt_wa(
    const float* __restrict__ W, __hip_bfloat16* __restrict__ Wb,
    const float* __restrict__ A, __hip_bfloat16* __restrict__ Ab) {
    int b = blockIdx.x;
    if (b < 1024) {
        int i = b * 256 + threadIdx.x;
        const int n8 = N_DIM * K_DIM / 8;
        const int stride = 1024 * 256;
        for (; i < n8; i += stride) {
            const float4* p = (const float4*)(W + (size_t)i * 8);
            float4 v0 = p[0], v1 = p[1];
            bf16x8 o;
            o[0] = (__bf16)v0.x; o[1] = (__bf16)v0.y; o[2] = (__bf16)v0.z; o[3] = (__bf16)v0.w;
            o[4] = (__bf16)v1.x; o[5] = (__bf16)v1.y; o[6] = (__bf16)v1.z; o[7] = (__bf16)v1.w;
            *(bf16x8*)((__hip_bfloat16*)Wb + (size_t)i * 8) = o;
        }
    } else {
        int i = (b - 1024) * 256 + threadIdx.x;
        if (i < 8 * K_DIM / 8) {
            const float4* p = (const float4*)(A + (size_t)i * 8);
            float4 v0 = p[0], v1 = p[1];
            bf16x8 o;
            o[0] = (__bf16)v0.x; o[1] = (__bf16)v0.y; o[2] = (__bf16)v0.z; o[3] = (__bf16)v0.w;
            o[4] = (__bf16)v1.x; o[5] = (__bf16)v1.y; o[6] = (__bf16)v1.z; o[7] = (__bf16)v1.w;
            *(bf16x8*)((__hip_bfloat16*)Ab + (size_t)i * 8) = o;
        }
    }
}

// ---------------- fused: x -> Xb (bf16) AND xa[m][r] = 2*mask*dot(x[m],A[r]) ----------------
__global__ __launch_bounds__(256) void cvt_x_xa(
    const float* __restrict__ x, const int* __restrict__ ids,
    const __hip_bfloat16* __restrict__ Abf,   // [8,4096] bf16
    __hip_bfloat16* __restrict__ Xb, float* __restrict__ xa) {
    __shared__ __hip_bfloat16 As[8 * 4096];   // 64 KiB
    int tid = threadIdx.x;
    for (int i = tid; i < 8 * 4096 / 8; i += 256)
        *(bf16x8*)(As + i * 8) = *(const bf16x8*)(Abf + i * 8);
    __syncthreads();

    int wave = tid >> 6, lane = tid & 63;
#pragma unroll
    for (int rr = 0; rr < 2; rr++) {
        int row = blockIdx.x * 8 + wave * 2 + rr;
        const float* xr = x + (size_t)row * K_DIM;
        __hip_bfloat16* xo = Xb + (size_t)row * K_DIM;
        float s[8] = {0.f, 0.f, 0.f, 0.f, 0.f, 0.f, 0.f, 0.f};
#pragma unroll
        for (int j = 0; j < 8; j++) {
            int k = j * 512 + lane * 8;
            float4 v0 = *(const float4*)(xr + k);
            float4 v1 = *(const float4*)(xr + k + 4);
            bf16x8 o;
            o[0] = (__bf16)v0.x; o[1] = (__bf16)v0.y; o[2] = (__bf16)v0.z; o[3] = (__bf16)v0.w;
            o[4] = (__bf16)v1.x; o[5] = (__bf16)v1.y; o[6] = (__bf16)v1.z; o[7] = (__bf16)v1.w;
            *(bf16x8*)(xo + k) = o;
#pragma unroll
            for (int r = 0; r < 8; r++) {
                bf16x8 av = *(const bf16x8*)(As + r * 4096 + k);
                s[r] += v0.x * (float)av[0] + v0.y * (float)av[1] + v0.z * (float)av[2] + v0.w * (float)av[3]
                      + v1.x * (float)av[4] + v1.y * (float)av[5] + v1.z * (float)av[6] + v1.w * (float)av[7];
            }
        }
#pragma unroll
        for (int r = 0; r < 8; r++) {
            float v = s[r];
            for (int off = 32; off; off >>= 1) v += __shfl_down(v, off);
            s[r] = v;
        }
        if (lane == 0) {
            float gate = (ids[row] == 7) ? 2.0f : 0.0f;
#pragma unroll
            for (int r = 0; r < 8; r++) xa[(size_t)row * 8 + r] = s[r] * gate;
        }
    }
}

// ---------------- main GEMM ----------------
#define LGKMW(n) asm volatile("s_waitcnt lgkmcnt(" #n ")" ::: "memory")
#define VMCW(n)  asm volatile("s_waitcnt vmcnt(" #n ")" ::: "memory")
#define SB0()    __builtin_amdgcn_sched_barrier(0)
#define BAR()    __builtin_amdgcn_s_barrier()
#define PRIO(p)  __builtin_amdgcn_s_setprio(p)

#define GLD(gp, lp) __builtin_amdgcn_global_load_lds(                           \
    (const __attribute__((address_space(1))) unsigned int*)(gp),                \
    (__attribute__((address_space(3))) unsigned int*)(lp), 16, 0, 0)

// LDS layout (144 KiB) — identical to R12:
//   [0, 48K):    A-m0 ring, 3 slots of 16 KiB (slot = kt % 3)
//   [48K, 80K):  A-m1, 2 buffers of 16 KiB (buf = kt & 1)
//   [80K, 144K): B, 2 buffers of 32 KiB (buf = kt & 1)
// Rows 128 B; 8 chunks of 16 B at position p = chunk ^ (row&7).
__global__ __launch_bounds__(512, 1) void gemm_bias_lora(
    const __hip_bfloat16* __restrict__ Xb,   // [M, K]
    const __hip_bfloat16* __restrict__ Wb,   // [N, K]
    const float* __restrict__ bias,          // [N]
    const float* __restrict__ xa,            // [M, 8] pre-scaled & gated
    const float* __restrict__ loraB,         // [N, 8]
    float* __restrict__ out) {
    __shared__ char smem[147456];            // 144 KiB

    int tid = threadIdx.x;
    int bid = blockIdx.x;
    int swz = (bid & 7) * 128 + (bid >> 3);  // XCD-bijective, nwg=1024
    int n_tile = swz & 15;
    int m_tile = swz >> 4;
    int m_base = m_tile * BM, n_base = n_tile * BN;
    int wave = tid >> 6, lane = tid & 63;
    int wr = wave >> 2, wc = wave & 3;       // 2M x 4N waves, per-wave 128x64
    int l15 = lane & 15, lhi = lane >> 4;
    int l8 = lane >> 3;
    int cx = ((lane & 7) ^ l8) * 16;          // staging source chunk (inverse swizzle)
    int pswz0 = ((lhi)     ^ (l15 & 7)) * 16; // read chunk byte, ks=0
    int pswz1 = ((4 + lhi) ^ (l15 & 7)) * 16; // read chunk byte, ks=1

    f32x4 acc[8][4] = {};

    const char* Abase = (const char*)(Xb + (size_t)m_base * K_DIM);
    const char* Bbase = (const char*)(Wb + (size_t)n_base * K_DIM);

    // --- per-thread global stage base pointers (include cx); bumped +768/6 tiles ---
    int rlj0 = (wave * 2 + 0) * 8 + l8;       // unit-local row, j=0
    int rlj1 = (wave * 2 + 1) * 8 + l8;       // j=1
    auto arow = [&](int mq, int rl) { return (rl < 64) ? (mq * 64 + rl) : (128 + mq * 64 + (rl - 64)); };
    const char* gA00 = Abase + (size_t)arow(0, rlj0) * 8192 + cx;
    const char* gA01 = Abase + (size_t)arow(0, rlj1) * 8192 + cx;
    const char* gA10 = Abase + (size_t)arow(1, rlj0) * 8192 + cx;
    const char* gA11 = Abase + (size_t)arow(1, rlj1) * 8192 + cx;
    const char* gB00 = Bbase + (size_t)rlj0 * 8192 + cx;            // h=0
    const char* gB01 = Bbase + (size_t)rlj1 * 8192 + cx;
    const char* gB10 = Bbase + (size_t)(128 + rlj0) * 8192 + cx;    // h=1
    const char* gB11 = Bbase + (size_t)(128 + rlj1) * 8192 + cx;

    // --- per-thread LDS stage destinations (slot/buf offsets are literals) ---
    char* sd0 = smem + (wave * 2 + 0) * 1024 + lane * 16;
    char* sd1 = sd0 + 1024;

    // --- per-thread LDS read base pointers (offsets become ds_read literals) ---
    const char* aR0   = smem + (wr * 64 + l15) * 128 + pswz0;
    const char* aR1   = smem + (wr * 64 + l15) * 128 + pswz1;
    const char* aR0m1 = aR0 + 49152;
    const char* aR1m1 = aR1 + 49152;
    const char* bR0   = smem + 81920 + (wc * 64 + l15) * 128 + pswz0;
    const char* bR1   = smem + 81920 + (wc * 64 + l15) * 128 + pswz1;

#define STAGE_AM0(K, SLOT) do { GLD(gA00 + (K) * 128, sd0 + (SLOT) * 16384);                 \
                                GLD(gA01 + (K) * 128, sd1 + (SLOT) * 16384); } while (0)
#define STAGE_AM1(K, B_)   do { GLD(gA10 + (K) * 128, sd0 + 49152 + (B_) * 16384);           \
                                GLD(gA11 + (K) * 128, sd1 + 49152 + (B_) * 16384); } while (0)
#define STAGE_B0(K, B_)    do { GLD(gB00 + (K) * 128, sd0 + 81920 + (B_) * 32768);           \
                                GLD(gB01 + (K) * 128, sd1 + 81920 + (B_) * 32768); } while (0)
#define STAGE_B1(K, B_)    do { GLD(gB10 + (K) * 128, sd0 + 81920 + (B_) * 32768 + 16384);   \
                                GLD(gB11 + (K) * 128, sd1 + 81920 + (B_) * 32768 + 16384); } while (0)

#define MFMA16(AF, BF, RO)                                                                    \
    _Pragma("unroll")                                                                         \
    for (int mi = 0; mi < 4; mi++) {                                                          \
        _Pragma("unroll")                                                                     \
        for (int ni = 0; ni < 4; ni++)                                                        \
            acc[(RO) + mi][ni] = __builtin_amdgcn_mfma_f32_16x16x32_bf16((AF)[mi], (BF)[ni],  \
                                                                acc[(RO) + mi][ni], 0, 0, 0); \
    }

    // Wait ledger identical to R12: LGKM 4/8/4/0 per phase; VMCW(2) + 1 BAR per tile.
#define TILE_BODY(K, S0C, CBC, G1, G2, VM2) do {                                              \
    bf16x8 af0[4], af1[4], bf0[4], bf1[4];                                                    \
    _Pragma("unroll")                                                                         \
    for (int mi = 0; mi < 4; mi++) af0[mi] = *(const bf16x8*)(aR0 + (S0C) * 16384 + mi * 2048);   \
    _Pragma("unroll")                                                                         \
    for (int ni = 0; ni < 4; ni++) bf0[ni] = *(const bf16x8*)(bR0 + (CBC) * 32768 + ni * 2048);   \
    _Pragma("unroll")                                                                         \
    for (int mi = 0; mi < 4; mi++) af1[mi] = *(const bf16x8*)(aR0m1 + (CBC) * 16384 + mi * 2048); \
    if (G1) { STAGE_B0((K) + 1, (CBC) ^ 1); }                                                 \
    LGKMW(4); SB0(); PRIO(1); MFMA16(af0, bf0, 0) PRIO(0);                                    \
    _Pragma("unroll")                                                                         \
    for (int mi = 0; mi < 4; mi++) af0[mi] = *(const bf16x8*)(aR1 + (S0C) * 16384 + mi * 2048);   \
    _Pragma("unroll")                                                                         \
    for (int ni = 0; ni < 4; ni++) bf1[ni] = *(const bf16x8*)(bR1 + (CBC) * 32768 + ni * 2048);   \
    if (G1) { STAGE_B1((K) + 1, (CBC) ^ 1); STAGE_AM1((K) + 1, (CBC) ^ 1); }                  \
    LGKMW(8); SB0(); PRIO(1); MFMA16(af1, bf0, 4) PRIO(0);                                    \
    _Pragma("unroll")                                                                         \
    for (int mi = 0; mi < 4; mi++) af1[mi] = *(const bf16x8*)(aR1m1 + (CBC) * 16384 + mi * 2048); \
    LGKMW(4); SB0(); PRIO(1); MFMA16(af0, bf1, 0) PRIO(0);                                    \
    if (G2) { STAGE_AM0((K) + 2, ((S0C) + 2) % 3); }                                          \
    LGKMW(0); SB0(); PRIO(1); MFMA16(af1, bf1, 4) PRIO(0);                                    \
    if (VM2) { VMCW(2); } else { VMCW(0); }                                                   \
    BAR();                                                                                    \
} while (0)

    // prologue: tile0 {A-m0 s0, B h0/h1 b0, A-m1 b0} + A-m0(1) s1  (order = R12)
    STAGE_AM0(0, 0);
    STAGE_B0(0, 0); STAGE_B1(0, 0);
    STAGE_AM1(0, 0);
    STAGE_AM0(1, 1);
    VMCW(2);         // tile0's 8 retired; A-m0(1)'s 2 in flight
    BAR();

    // main loop: 10 iterations of 6 tiles (t = 0..59); (s0,cb) = (k%3, k&1)
    for (int it = 0; it < 10; it++) {
        TILE_BODY(0, 0, 0, 1, 1, 1);
        TILE_BODY(1, 1, 1, 1, 1, 1);
        TILE_BODY(2, 2, 0, 1, 1, 1);
        TILE_BODY(3, 0, 1, 1, 1, 1);
        TILE_BODY(4, 1, 0, 1, 1, 1);
        TILE_BODY(5, 2, 1, 1, 1, 1);
        gA00 += 768; gA01 += 768; gA10 += 768; gA11 += 768;
        gB00 += 768; gB01 += 768; gB10 += 768; gB11 += 768;
    }
    // tail: tiles 60..63 (pointers now at tile-60 window)
    TILE_BODY(0, 0, 0, 1, 1, 1);   // t=60
    TILE_BODY(1, 1, 1, 1, 1, 1);   // t=61
    TILE_BODY(2, 2, 0, 1, 0, 0);   // t=62: no A-m0 stage, drain
    TILE_BODY(3, 0, 1, 0, 0, 0);   // t=63: no stages, drain

#undef TILE_BODY
#undef MFMA16
#undef STAGE_AM0
#undef STAGE_AM1
#undef STAGE_B0
#undef STAGE_B1

    // epilogue: C/D layout col = lane&15, row = (lane>>4)*4 + reg
    int wrow = m_base + wr * 128;
    int wcol = n_base + wc * 64;
    float bv[4];
    float4 lb0[4], lb1[4];
#pragma unroll
    for (int ni = 0; ni < 4; ni++) {
        int n = wcol + ni * 16 + l15;
        bv[ni] = bias[n];
        lb0[ni] = *(const float4*)(loraB + (size_t)n * 8);
        lb1[ni] = *(const float4*)(loraB + (size_t)n * 8 + 4);
    }
#pragma unroll
    for (int mi = 0; mi < 8; mi++) {
#pragma unroll
        for (int r = 0; r < 4; r++) {
            int m = wrow + mi * 16 + lhi * 4 + r;
            float4 xa0 = *(const float4*)(xa + (size_t)m * 8);
            float4 xa1 = *(const float4*)(xa + (size_t)m * 8 + 4);
#pragma unroll
            for (int ni = 0; ni < 4; ni++) {
                int n = wcol + ni * 16 + l15;
                float lora = xa0.x * lb0[ni].x + xa0.y * lb0[ni].y + xa0.z * lb0[ni].z + xa0.w * lb0[ni].w
                           + xa1.x * lb1[ni].x + xa1.y * lb1[ni].y + xa1.z * lb1[ni].z + xa1.w * lb1[ni].w;
                out[(size_t)m * N_DIM + n] = acc[mi][ni][r] + bv[ni] + lora;
            }
        }
    }
}

// ---------------- fallback (ws too small): correct but slow ----------------
__global__ void fallback_kernel(const float* __restrict__ x, const int* __restrict__ ids,
                                const float* __restrict__ W, const float* __restrict__ b,
                                const float* __restrict__ A, const float* __restrict__ B8,
                                float* __restrict__ out) {
    __shared__ float xs[K_DIM];
    __shared__ float xa_s[8];
    int row = blockIdx.y;
    int t = threadIdx.x;
    const float* xr = x + (size_t)row * K_DIM;
    for (int k = t; k < K_DIM; k += 256) xs[k] = xr[k];
    __syncthreads();
    if (t < 8) {
        float s = 0.f;
        for (int k = 0; k < K_DIM; k++) s += xs[k] * A[t * K_DIM + k];
        xa_s[t] = (ids[row] == 7) ? s * 2.0f : 0.0f;
    }
    __syncthreads();
    int col = blockIdx.x * 256 + t;
    const float* wr = W + (size_t)col * K_DIM;
    float acc = 0.f;
    for (int k = 0; k < K_DIM; k++) acc += xs[k] * wr[k];
    float lora = 0.f;
#pragma unroll
    for (int rr = 0; rr < 8; rr++) lora += xa_s[rr] * B8[col * 8 + rr];
    out[(size_t)row * N_DIM + col] = acc + b[col] + lora;
}

extern "C" void kernel_launch(void* const* d_in, const int* in_sizes, int n_in,
                              void* d_out, int out_size, void* d_ws, size_t ws_size,
                              hipStream_t stream) {
    const float* x   = (const float*)d_in[0];
    const int*   ids = (const int*)d_in[1];
    const float* W   = (const float*)d_in[2];
    const float* b   = (const float*)d_in[3];
    const float* lA  = (const float*)d_in[4];
    const float* lB  = (const float*)d_in[5];
    float* out = (float*)d_out;

    size_t wb_bytes = (size_t)N_DIM * K_DIM * 2;          // 32 MiB
    size_t xb_bytes = (size_t)M_DIM * K_DIM * 2;          // 128 MiB
    size_t xa_bytes = (size_t)M_DIM * 8 * 4;              // 0.5 MiB
    size_t ab_bytes = (size_t)8 * K_DIM * 2;              // 64 KiB

    if (ws_size >= wb_bytes + xb_bytes + xa_bytes + ab_bytes) {
        __hip_bfloat16* Wb  = (__hip_bfloat16*)d_ws;
        __hip_bfloat16* Xb  = (__hip_bfloat16*)((char*)d_ws + wb_bytes);
        float*          xav = (float*)((char*)d_ws + wb_bytes + xb_bytes);
        __hip_bfloat16* Abf = (__hip_bfloat16*)((char*)d_ws + wb_bytes + xb_bytes + xa_bytes);

        cvt_wa<<<1024 + 16, 256, 0, stream>>>(W, Wb, lA, Abf);
        cvt_x_xa<<<M_DIM / 8, 256, 0, stream>>>(x, ids, Abf, Xb, xav);
        gemm_bias_lora<<<(M_DIM / BM) * (N_DIM / BN), 512, 0, stream>>>(Xb, Wb, b, xav, lB, out);
    } else {
        fallback_kernel<<<dim3(N_DIM / 256, M_DIM), 256, 0, stream>>>(x, ids, W, b, lA, lB, out);
    }
}

// Round 19
// 560.321 us; speedup vs baseline: 4.0794x; 1.0085x over previous
//
#include <hip/hip_runtime.h>
#include <hip/hip_bf16.h>
#include <stdint.h>

// ConditionalLoRALinear: out = x@W^T + b + mask*(2*(x@A^T)@B^T)
// M=16384, K=4096, N=4096, R=8. bf16 MFMA path.
// R19: GEMM = verified R18 (457us @ MfmaUtil 58.5, strength-reduced unroll-6).
//      Prep fused into ONE launch (3072 blocks): blocks 0..2047 convert x->bf16
//      + compute xa (each block converts f32 lora_A into its own LDS copy --
//      removes the Abf cross-kernel dependency); blocks 2048..3071 convert W.

typedef __attribute__((ext_vector_type(8))) __bf16 bf16x8;
typedef __attribute__((ext_vector_type(4))) float f32x4;

#define M_DIM 16384
#define K_DIM 4096
#define N_DIM 4096
#define BM 256
#define BN 256
#define BK 64
#define NT2 (K_DIM / BK)   // 64

// ---------------- fused prep: x->Xb + xa (blocks 0..2047), W->Wb (2048..3071) ----------------
__global__ __launch_bounds__(256) void prep_all(
    const float* __restrict__ x, const int* __restrict__ ids,
    const float* __restrict__ W, const float* __restrict__ lA,
    __hip_bfloat16* __restrict__ Wb, __hip_bfloat16* __restrict__ Xb,
    float* __restrict__ xa) {
    __shared__ __hip_bfloat16 As[8 * 4096];   // 64 KiB (unused by W-blocks)
    int tid = threadIdx.x;
    int b = blockIdx.x;

    if (b >= 2048) {
        // ---- W conversion: 1024 blocks, grid-stride ----
        int i = (b - 2048) * 256 + tid;
        const int n8 = N_DIM * K_DIM / 8;
        const int stride = 1024 * 256;
        for (; i < n8; i += stride) {
            const float4* p = (const float4*)(W + (size_t)i * 8);
            float4 v0 = p[0], v1 = p[1];
            bf16x8 o;
            o[0] = (__bf16)v0.x; o[1] = (__bf16)v0.y; o[2] = (__bf16)v0.z; o[3] = (__bf16)v0.w;
            o[4] = (__bf16)v1.x; o[5] = (__bf16)v1.y; o[6] = (__bf16)v1.z; o[7] = (__bf16)v1.w;
            *(bf16x8*)((__hip_bfloat16*)Wb + (size_t)i * 8) = o;
        }
        return;
    }

    // ---- x conversion + xa: convert lora_A (f32, L3-resident) into LDS bf16 ----
    for (int i = tid; i < 8 * 4096 / 8; i += 256) {
        const float4* p = (const float4*)(lA + (size_t)i * 8);
        float4 v0 = p[0], v1 = p[1];
        bf16x8 o;
        o[0] = (__bf16)v0.x; o[1] = (__bf16)v0.y; o[2] = (__bf16)v0.z; o[3] = (__bf16)v0.w;
        o[4] = (__bf16)v1.x; o[5] = (__bf16)v1.y; o[6] = (__bf16)v1.z; o[7] = (__bf16)v1.w;
        *(bf16x8*)(As + i * 8) = o;
    }
    __syncthreads();

    int wave = tid >> 6, lane = tid & 63;
#pragma unroll
    for (int rr = 0; rr < 2; rr++) {
        int row = b * 8 + wave * 2 + rr;
        const float* xr = x + (size_t)row * K_DIM;
        __hip_bfloat16* xo = Xb + (size_t)row * K_DIM;
        float s[8] = {0.f, 0.f, 0.f, 0.f, 0.f, 0.f, 0.f, 0.f};
#pragma unroll
        for (int j = 0; j < 8; j++) {
            int k = j * 512 + lane * 8;
            float4 v0 = *(const float4*)(xr + k);
            float4 v1 = *(const float4*)(xr + k + 4);
            bf16x8 o;
            o[0] = (__bf16)v0.x; o[1] = (__bf16)v0.y; o[2] = (__bf16)v0.z; o[3] = (__bf16)v0.w;
            o[4] = (__bf16)v1.x; o[5] = (__bf16)v1.y; o[6] = (__bf16)v1.z; o[7] = (__bf16)v1.w;
            *(bf16x8*)(xo + k) = o;
#pragma unroll
            for (int r = 0; r < 8; r++) {
                bf16x8 av = *(const bf16x8*)(As + r * 4096 + k);
                s[r] += v0.x * (float)av[0] + v0.y * (float)av[1] + v0.z * (float)av[2] + v0.w * (float)av[3]
                      + v1.x * (float)av[4] + v1.y * (float)av[5] + v1.z * (float)av[6] + v1.w * (float)av[7];
            }
        }
#pragma unroll
        for (int r = 0; r < 8; r++) {
            float v = s[r];
            for (int off = 32; off; off >>= 1) v += __shfl_down(v, off);
            s[r] = v;
        }
        if (lane == 0) {
            float gate = (ids[row] == 7) ? 2.0f : 0.0f;
#pragma unroll
            for (int r = 0; r < 8; r++) xa[(size_t)row * 8 + r] = s[r] * gate;
        }
    }
}

// ---------------- main GEMM (VERIFIED R18 kernel, byte-identical) ----------------
#define LGKMW(n) asm volatile("s_waitcnt lgkmcnt(" #n ")" ::: "memory")
#define VMCW(n)  asm volatile("s_waitcnt vmcnt(" #n ")" ::: "memory")
#define SB0()    __builtin_amdgcn_sched_barrier(0)
#define BAR()    __builtin_amdgcn_s_barrier()
#define PRIO(p)  __builtin_amdgcn_s_setprio(p)

#define GLD(gp, lp) __builtin_amdgcn_global_load_lds(                           \
    (const __attribute__((address_space(1))) unsigned int*)(gp),                \
    (__attribute__((address_space(3))) unsigned int*)(lp), 16, 0, 0)

// LDS layout (144 KiB):
//   [0, 48K):    A-m0 ring, 3 slots of 16 KiB (slot = kt % 3)
//   [48K, 80K):  A-m1, 2 buffers of 16 KiB (buf = kt & 1)
//   [80K, 144K): B, 2 buffers of 32 KiB (buf = kt & 1)
// Rows 128 B; 8 chunks of 16 B at position p = chunk ^ (row&7).
__global__ __launch_bounds__(512, 1) void gemm_bias_lora(
    const __hip_bfloat16* __restrict__ Xb,   // [M, K]
    const __hip_bfloat16* __restrict__ Wb,   // [N, K]
    const float* __restrict__ bias,          // [N]
    const float* __restrict__ xa,            // [M, 8] pre-scaled & gated
    const float* __restrict__ loraB,         // [N, 8]
    float* __restrict__ out) {
    __shared__ char smem[147456];            // 144 KiB

    int tid = threadIdx.x;
    int bid = blockIdx.x;
    int swz = (bid & 7) * 128 + (bid >> 3);  // XCD-bijective, nwg=1024
    int n_tile = swz & 15;
    int m_tile = swz >> 4;
    int m_base = m_tile * BM, n_base = n_tile * BN;
    int wave = tid >> 6, lane = tid & 63;
    int wr = wave >> 2, wc = wave & 3;       // 2M x 4N waves, per-wave 128x64
    int l15 = lane & 15, lhi = lane >> 4;
    int l8 = lane >> 3;
    int cx = ((lane & 7) ^ l8) * 16;          // staging source chunk (inverse swizzle)
    int pswz0 = ((lhi)     ^ (l15 & 7)) * 16; // read chunk byte, ks=0
    int pswz1 = ((4 + lhi) ^ (l15 & 7)) * 16; // read chunk byte, ks=1

    f32x4 acc[8][4] = {};

    const char* Abase = (const char*)(Xb + (size_t)m_base * K_DIM);
    const char* Bbase = (const char*)(Wb + (size_t)n_base * K_DIM);

    // --- per-thread global stage base pointers (include cx); bumped +768/6 tiles ---
    int rlj0 = (wave * 2 + 0) * 8 + l8;       // unit-local row, j=0
    int rlj1 = (wave * 2 + 1) * 8 + l8;       // j=1
    auto arow = [&](int mq, int rl) { return (rl < 64) ? (mq * 64 + rl) : (128 + mq * 64 + (rl - 64)); };
    const char* gA00 = Abase + (size_t)arow(0, rlj0) * 8192 + cx;
    const char* gA01 = Abase + (size_t)arow(0, rlj1) * 8192 + cx;
    const char* gA10 = Abase + (size_t)arow(1, rlj0) * 8192 + cx;
    const char* gA11 = Abase + (size_t)arow(1, rlj1) * 8192 + cx;
    const char* gB00 = Bbase + (size_t)rlj0 * 8192 + cx;            // h=0
    const char* gB01 = Bbase + (size_t)rlj1 * 8192 + cx;
    const char* gB10 = Bbase + (size_t)(128 + rlj0) * 8192 + cx;    // h=1
    const char* gB11 = Bbase + (size_t)(128 + rlj1) * 8192 + cx;

    // --- per-thread LDS stage destinations (slot/buf offsets are literals) ---
    char* sd0 = smem + (wave * 2 + 0) * 1024 + lane * 16;
    char* sd1 = sd0 + 1024;

    // --- per-thread LDS read base pointers (offsets become ds_read literals) ---
    const char* aR0   = smem + (wr * 64 + l15) * 128 + pswz0;
    const char* aR1   = smem + (wr * 64 + l15) * 128 + pswz1;
    const char* aR0m1 = aR0 + 49152;
    const char* aR1m1 = aR1 + 49152;
    const char* bR0   = smem + 81920 + (wc * 64 + l15) * 128 + pswz0;
    const char* bR1   = smem + 81920 + (wc * 64 + l15) * 128 + pswz1;

#define STAGE_AM0(K, SLOT) do { GLD(gA00 + (K) * 128, sd0 + (SLOT) * 16384);                 \
                                GLD(gA01 + (K) * 128, sd1 + (SLOT) * 16384); } while (0)
#define STAGE_AM1(K, B_)   do { GLD(gA10 + (K) * 128, sd0 + 49152 + (B_) * 16384);           \
                                GLD(gA11 + (K) * 128, sd1 + 49152 + (B_) * 16384); } while (0)
#define STAGE_B0(K, B_)    do { GLD(gB00 + (K) * 128, sd0 + 81920 + (B_) * 32768);           \
                                GLD(gB01 + (K) * 128, sd1 + 81920 + (B_) * 32768); } while (0)
#define STAGE_B1(K, B_)    do { GLD(gB10 + (K) * 128, sd0 + 81920 + (B_) * 32768 + 16384);   \
                                GLD(gB11 + (K) * 128, sd1 + 81920 + (B_) * 32768 + 16384); } while (0)

#define MFMA16(AF, BF, RO)                                                                    \
    _Pragma("unroll")                                                                         \
    for (int mi = 0; mi < 4; mi++) {                                                          \
        _Pragma("unroll")                                                                     \
        for (int ni = 0; ni < 4; ni++)                                                        \
            acc[(RO) + mi][ni] = __builtin_amdgcn_mfma_f32_16x16x32_bf16((AF)[mi], (BF)[ni],  \
                                                                acc[(RO) + mi][ni], 0, 0, 0); \
    }

    // Wait ledger identical to R12: LGKM 4/8/4/0 per phase; VMCW(2) + 1 BAR per tile.
#define TILE_BODY(K, S0C, CBC, G1, G2, VM2) do {                                              \
    bf16x8 af0[4], af1[4], bf0[4], bf1[4];                                                    \
    _Pragma("unroll")                                                                         \
    for (int mi = 0; mi < 4; mi++) af0[mi] = *(const bf16x8*)(aR0 + (S0C) * 16384 + mi * 2048);   \
    _Pragma("unroll")                                                                         \
    for (int ni = 0; ni < 4; ni++) bf0[ni] = *(const bf16x8*)(bR0 + (CBC) * 32768 + ni * 2048);   \
    _Pragma("unroll")                                                                         \
    for (int mi = 0; mi < 4; mi++) af1[mi] = *(const bf16x8*)(aR0m1 + (CBC) * 16384 + mi * 2048); \
    if (G1) { STAGE_B0((K) + 1, (CBC) ^ 1); }                                                 \
    LGKMW(4); SB0(); PRIO(1); MFMA16(af0, bf0, 0) PRIO(0);                                    \
    _Pragma("unroll")                                                                         \
    for (int mi = 0; mi < 4; mi++) af0[mi] = *(const bf16x8*)(aR1 + (S0C) * 16384 + mi * 2048);   \
    _Pragma("unroll")                                                                         \
    for (int ni = 0; ni < 4; ni++) bf1[ni] = *(const bf16x8*)(bR1 + (CBC) * 32768 + ni * 2048);   \
    if (G1) { STAGE_B1((K) + 1, (CBC) ^ 1); STAGE_AM1((K) + 1, (CBC) ^ 1); }                  \
    LGKMW(8); SB0(); PRIO(1); MFMA16(af1, bf0, 4) PRIO(0);                                    \
    _Pragma("unroll")                                                                         \
    for (int mi = 0; mi < 4; mi++) af1[mi] = *(const bf16x8*)(aR1m1 + (CBC) * 16384 + mi * 2048); \
    LGKMW(4); SB0(); PRIO(1); MFMA16(af0, bf1, 0) PRIO(0);                                    \
    if (G2) { STAGE_AM0((K) + 2, ((S0C) + 2) % 3); }                                          \
    LGKMW(0); SB0(); PRIO(1); MFMA16(af1, bf1, 4) PRIO(0);                                    \
    if (VM2) { VMCW(2); } else { VMCW(0); }                                                   \
    BAR();                                                                                    \
} while (0)

    // prologue: tile0 {A-m0 s0, B h0/h1 b0, A-m1 b0} + A-m0(1) s1
    STAGE_AM0(0, 0);
    STAGE_B0(0, 0); STAGE_B1(0, 0);
    STAGE_AM1(0, 0);
    STAGE_AM0(1, 1);
    VMCW(2);         // tile0's 8 retired; A-m0(1)'s 2 in flight
    BAR();

    // main loop: 10 iterations of 6 tiles (t = 0..59); (s0,cb) = (k%3, k&1)
    for (int it = 0; it < 10; it++) {
        TILE_BODY(0, 0, 0, 1, 1, 1);
        TILE_BODY(1, 1, 1, 1, 1, 1);
        TILE_BODY(2, 2, 0, 1, 1, 1);
        TILE_BODY(3, 0, 1, 1, 1, 1);
        TILE_BODY(4, 1, 0, 1, 1, 1);
        TILE_BODY(5, 2, 1, 1, 1, 1);
        gA00 += 768; gA01 += 768; gA10 += 768; gA11 += 768;
        gB00 += 768; gB01 += 768; gB10 += 768; gB11 += 768;
    }
    // tail: tiles 60..63 (pointers now at tile-60 window)
    TILE_BODY(0, 0, 0, 1, 1, 1);   // t=60
    TILE_BODY(1, 1, 1, 1, 1, 1);   // t=61
    TILE_BODY(2, 2, 0, 1, 0, 0);   // t=62: no A-m0 stage, drain
    TILE_BODY(3, 0, 1, 0, 0, 0);   // t=63: no stages, drain

#undef TILE_BODY
#undef MFMA16
#undef STAGE_AM0
#undef STAGE_AM1
#undef STAGE_B0
#undef STAGE_B1

    // epilogue: C/D layout col = lane&15, row = (lane>>4)*4 + reg
    int wrow = m_base + wr * 128;
    int wcol = n_base + wc * 64;
    float bv[4];
    float4 lb0[4], lb1[4];
#pragma unroll
    for (int ni = 0; ni < 4; ni++) {
        int n = wcol + ni * 16 + l15;
        bv[ni] = bias[n];
        lb0[ni] = *(const float4*)(loraB + (size_t)n * 8);
        lb1[ni] = *(const float4*)(loraB + (size_t)n * 8 + 4);
    }
#pragma unroll
    for (int mi = 0; mi < 8; mi++) {
#pragma unroll
        for (int r = 0; r < 4; r++) {
            int m = wrow + mi * 16 + lhi * 4 + r;
            float4 xa0 = *(const float4*)(xa + (size_t)m * 8);
            float4 xa1 = *(const float4*)(xa + (size_t)m * 8 + 4);
#pragma unroll
            for (int ni = 0; ni < 4; ni++) {
                int n = wcol + ni * 16 + l15;
                float lora = xa0.x * lb0[ni].x + xa0.y * lb0[ni].y + xa0.z * lb0[ni].z + xa0.w * lb0[ni].w
                           + xa1.x * lb1[ni].x + xa1.y * lb1[ni].y + xa1.z * lb1[ni].z + xa1.w * lb1[ni].w;
                out[(size_t)m * N_DIM + n] = acc[mi][ni][r] + bv[ni] + lora;
            }
        }
    }
}

// ---------------- fallback (ws too small): correct but slow ----------------
__global__ void fallback_kernel(const float* __restrict__ x, const int* __restrict__ ids,
                                const float* __restrict__ W, const float* __restrict__ b,
                                const float* __restrict__ A, const float* __restrict__ B8,
                                float* __restrict__ out) {
    __shared__ float xs[K_DIM];
    __shared__ float xa_s[8];
    int row = blockIdx.y;
    int t = threadIdx.x;
    const float* xr = x + (size_t)row * K_DIM;
    for (int k = t; k < K_DIM; k += 256) xs[k] = xr[k];
    __syncthreads();
    if (t < 8) {
        float s = 0.f;
        for (int k = 0; k < K_DIM; k++) s += xs[k] * A[t * K_DIM + k];
        xa_s[t] = (ids[row] == 7) ? s * 2.0f : 0.0f;
    }
    __syncthreads();
    int col = blockIdx.x * 256 + t;
    const float* wr = W + (size_t)col * K_DIM;
    float acc = 0.f;
    for (int k = 0; k < K_DIM; k++) acc += xs[k] * wr[k];
    float lora = 0.f;
#pragma unroll
    for (int rr = 0; rr < 8; rr++) lora += xa_s[rr] * B8[col * 8 + rr];
    out[(size_t)row * N_DIM + col] = acc + b[col] + lora;
}

extern "C" void kernel_launch(void* const* d_in, const int* in_sizes, int n_in,
                              void* d_out, int out_size, void* d_ws, size_t ws_size,
                              hipStream_t stream) {
    const float* x   = (const float*)d_in[0];
    const int*   ids = (const int*)d_in[1];
    const float* W   = (const float*)d_in[2];
    const float* b   = (const float*)d_in[3];
    const float* lA  = (const float*)d_in[4];
    const float* lB  = (const float*)d_in[5];
    float* out = (float*)d_out;

    size_t wb_bytes = (size_t)N_DIM * K_DIM * 2;          // 32 MiB
    size_t xb_bytes = (size_t)M_DIM * K_DIM * 2;          // 128 MiB
    size_t xa_bytes = (size_t)M_DIM * 8 * 4;              // 0.5 MiB

    if (ws_size >= wb_bytes + xb_bytes + xa_bytes) {
        __hip_bfloat16* Wb  = (__hip_bfloat16*)d_ws;
        __hip_bfloat16* Xb  = (__hip_bfloat16*)((char*)d_ws + wb_bytes);
        float*          xav = (float*)((char*)d_ws + wb_bytes + xb_bytes);

        prep_all<<<3072, 256, 0, stream>>>(x, ids, W, lA, Wb, Xb, xav);
        gemm_bias_lora<<<(M_DIM / BM) * (N_DIM / BN), 512, 0, stream>>>(Xb, Wb, b, xav, lB, out);
    } else {
        fallback_kernel<<<dim3(N_DIM / 256, M_DIM), 256, 0, stream>>>(x, ids, W, b, lA, lB, out);
    }
}